// Round 1
// baseline (708.618 us; speedup 1.0000x reference)
//
#include <hip/hip_runtime.h>
#include <math.h>

#define N_NODES 50000
#define N_EDGES 500000
#define IN_CH 256
#define D1 512          // HEADS*HID
#define HEADS 8
#define HID 64
#define OUT_CH 16
#define NEG_SLOPE 0.2f

// ---------------- GEMM1: h1[N,512] = x[N,256] @ W1[256,512] (fp32 tiled) ----
__global__ __launch_bounds__(256) void k_gemm1(const float* __restrict__ X,
                                               const float* __restrict__ W,
                                               float* __restrict__ H) {
    const int BM = 64, BN = 64, BK = 16;
    __shared__ float As[BK][BM];   // transposed: As[k][m]
    __shared__ float Bs[BK][BN];
    int bm = blockIdx.x;
    int bn = blockIdx.y;
    int tid = threadIdx.x;
    int tr = tid >> 4, tc = tid & 15;   // 16x16 thread grid, 4x4 per thread
    float acc[4][4] = {};
    int row0 = bm * BM;
    for (int k0 = 0; k0 < IN_CH; k0 += BK) {
        {   // load A tile 64x16 -> As[k][m]
            int r  = tid >> 2;          // 0..63
            int kq = (tid & 3) * 4;     // 0,4,8,12
            int gr = row0 + r;
            float4 v = (gr < N_NODES) ? *(const float4*)&X[(size_t)gr * IN_CH + k0 + kq]
                                      : make_float4(0.f, 0.f, 0.f, 0.f);
            As[kq + 0][r] = v.x; As[kq + 1][r] = v.y;
            As[kq + 2][r] = v.z; As[kq + 3][r] = v.w;
        }
        {   // load B tile 16x64
            int kk = tid >> 4;          // 0..15
            int nn = (tid & 15) * 4;
            *(float4*)&Bs[kk][nn] = *(const float4*)&W[(size_t)(k0 + kk) * D1 + bn * BN + nn];
        }
        __syncthreads();
        #pragma unroll
        for (int kk = 0; kk < BK; ++kk) {
            float4 a = *(const float4*)&As[kk][tr * 4];
            float4 b = *(const float4*)&Bs[kk][tc * 4];
            float av[4] = {a.x, a.y, a.z, a.w};
            float bv[4] = {b.x, b.y, b.z, b.w};
            #pragma unroll
            for (int i = 0; i < 4; ++i)
                #pragma unroll
                for (int j = 0; j < 4; ++j)
                    acc[i][j] += av[i] * bv[j];
        }
        __syncthreads();
    }
    #pragma unroll
    for (int i = 0; i < 4; ++i) {
        int gr = row0 + tr * 4 + i;
        if (gr < N_NODES) {
            float4 v = make_float4(acc[i][0], acc[i][1], acc[i][2], acc[i][3]);
            *(float4*)&H[(size_t)gr * D1 + bn * BN + tc * 4] = v;
        }
    }
}

// ---------------- per-node attention logits layer 1: a_src/a_dst [N,8] ------
__global__ __launch_bounds__(256) void k_att1(const float* __restrict__ H,
                                              const float* __restrict__ att_src,
                                              const float* __restrict__ att_dst,
                                              float* __restrict__ a_src,
                                              float* __restrict__ a_dst) {
    int wave = (blockIdx.x * blockDim.x + threadIdx.x) >> 6;
    int lane = threadIdx.x & 63;
    if (wave >= N_NODES) return;
    const float* hrow = H + (size_t)wave * D1 + lane * 8;
    float4 h0 = *(const float4*)hrow;
    float4 h1 = *(const float4*)(hrow + 4);
    float4 s0 = *(const float4*)&att_src[lane * 8];
    float4 s1 = *(const float4*)&att_src[lane * 8 + 4];
    float4 d0 = *(const float4*)&att_dst[lane * 8];
    float4 d1 = *(const float4*)&att_dst[lane * 8 + 4];
    float ps = h0.x * s0.x + h0.y * s0.y + h0.z * s0.z + h0.w * s0.w
             + h1.x * s1.x + h1.y * s1.y + h1.z * s1.z + h1.w * s1.w;
    float pd = h0.x * d0.x + h0.y * d0.y + h0.z * d0.z + h0.w * d0.w
             + h1.x * d1.x + h1.y * d1.y + h1.z * d1.z + h1.w * d1.w;
    #pragma unroll
    for (int off = 1; off < 8; off <<= 1) {
        ps += __shfl_xor(ps, off);
        pd += __shfl_xor(pd, off);
    }
    if ((lane & 7) == 0) {
        a_src[wave * HEADS + (lane >> 3)] = ps;
        a_dst[wave * HEADS + (lane >> 3)] = pd;
    }
}

// ---------------- CSR build ------------------------------------------------
__global__ void k_zero(int* __restrict__ deg) {
    int i = blockIdx.x * blockDim.x + threadIdx.x;
    if (i < N_NODES) deg[i] = 0;
}

__global__ void k_hist(const int* __restrict__ dst, int* __restrict__ deg) {
    int e = blockIdx.x * blockDim.x + threadIdx.x;
    if (e < N_EDGES) atomicAdd(&deg[dst[e]], 1);
}

__global__ __launch_bounds__(1024) void k_scan(const int* __restrict__ deg,
                                               int* __restrict__ offsets) {
    __shared__ int buf[1024];
    __shared__ int carry;
    int tid = threadIdx.x;
    if (tid == 0) carry = 0;
    __syncthreads();
    for (int base = 0; base < N_NODES; base += 1024) {
        int i = base + tid;
        int v = (i < N_NODES) ? deg[i] : 0;
        buf[tid] = v;
        __syncthreads();
        #pragma unroll
        for (int off = 1; off < 1024; off <<= 1) {
            int t = (tid >= off) ? buf[tid - off] : 0;
            __syncthreads();
            buf[tid] += t;
            __syncthreads();
        }
        int run = carry;
        if (i < N_NODES) offsets[i] = run + buf[tid] - v;   // exclusive
        __syncthreads();
        if (tid == 0) carry = run + buf[1023];
        __syncthreads();
    }
    if (tid == 0) offsets[N_NODES] = carry;
}

__global__ void k_copy(const int* __restrict__ src, int* __restrict__ dstp) {
    int i = blockIdx.x * blockDim.x + threadIdx.x;
    if (i < N_NODES) dstp[i] = src[i];
}

__global__ void k_scatter(const int* __restrict__ esrc, const int* __restrict__ edst,
                          int* __restrict__ cursor, int* __restrict__ csr) {
    int e = blockIdx.x * blockDim.x + threadIdx.x;
    if (e < N_EDGES) {
        int d = edst[e];
        int pos = atomicAdd(&cursor[d], 1);
        csr[pos] = esrc[e];
    }
}

// ---------------- layer-1 aggregation: online softmax, wave per node --------
__global__ __launch_bounds__(256) void k_agg1(const float* __restrict__ H,
                                              const float* __restrict__ a_src,
                                              const float* __restrict__ a_dst,
                                              const int* __restrict__ offsets,
                                              const int* __restrict__ csr,
                                              const float* __restrict__ b1,
                                              float* __restrict__ OUT) {
    int wave = (blockIdx.x * blockDim.x + threadIdx.x) >> 6;
    int lane = threadIdx.x & 63;
    if (wave >= N_NODES) return;
    int d = wave;
    int head = lane >> 3;
    float ad = a_dst[d * HEADS + head];
    // self-loop seed
    float es = a_src[d * HEADS + head] + ad;
    es = es > 0.f ? es : NEG_SLOPE * es;
    const float* hrow = H + (size_t)d * D1 + lane * 8;
    float4 t0 = *(const float4*)hrow;
    float4 t1 = *(const float4*)(hrow + 4);
    float o[8] = {t0.x, t0.y, t0.z, t0.w, t1.x, t1.y, t1.z, t1.w};
    float m = es, lsum = 1.0f;
    int beg = offsets[d], end = offsets[d + 1];
    for (int idx = beg; idx < end; ++idx) {
        int s = csr[idx];
        float e = a_src[s * HEADS + head] + ad;
        e = e > 0.f ? e : NEG_SLOPE * e;
        float mnew = fmaxf(m, e);
        float scale = __expf(m - mnew);
        float w = __expf(e - mnew);
        const float* hs = H + (size_t)s * D1 + lane * 8;
        float4 u0 = *(const float4*)hs;
        float4 u1 = *(const float4*)(hs + 4);
        lsum = lsum * scale + w;
        o[0] = o[0] * scale + w * u0.x; o[1] = o[1] * scale + w * u0.y;
        o[2] = o[2] * scale + w * u0.z; o[3] = o[3] * scale + w * u0.w;
        o[4] = o[4] * scale + w * u1.x; o[5] = o[5] * scale + w * u1.y;
        o[6] = o[6] * scale + w * u1.z; o[7] = o[7] * scale + w * u1.w;
        m = mnew;
    }
    float inv = 1.0f / (lsum + 1e-16f);
    float r[8];
    #pragma unroll
    for (int j = 0; j < 8; ++j) {
        float v = o[j] * inv + b1[lane * 8 + j];
        r[j] = v > 0.f ? v : expm1f(v);     // ELU
    }
    float* orow = OUT + (size_t)d * D1 + lane * 8;
    *(float4*)orow       = make_float4(r[0], r[1], r[2], r[3]);
    *(float4*)(orow + 4) = make_float4(r[4], r[5], r[6], r[7]);
}

// ---------------- GEMM2 + layer-2 attention logits -------------------------
__global__ __launch_bounds__(256) void k_gemm2(const float* __restrict__ A,
                                               const float* __restrict__ W,
                                               const float* __restrict__ as2v,
                                               const float* __restrict__ ad2v,
                                               float* __restrict__ H2,
                                               float* __restrict__ a_src2,
                                               float* __restrict__ a_dst2) {
    __shared__ float As[16 * 520];     // 16 rows, stride 520 (pad 8)
    __shared__ float Ws[512 * 16];
    int tid = threadIdx.x;
    int r = tid >> 4, c = tid & 15;
    int row0 = blockIdx.x * 16;
    #pragma unroll
    for (int i = 0; i < 8; ++i) {      // W2: 8192 floats
        int q = tid + i * 256;
        *(float4*)&Ws[q * 4] = *(const float4*)&W[q * 4];
    }
    #pragma unroll
    for (int i = 0; i < 8; ++i) {      // A tile: 16x512
        int q = tid + i * 256;
        int rr = q >> 7;
        int cc = (q & 127) * 4;
        int gr = row0 + rr;
        float4 v = (gr < N_NODES) ? *(const float4*)&A[(size_t)gr * D1 + cc]
                                  : make_float4(0.f, 0.f, 0.f, 0.f);
        *(float4*)&As[rr * 520 + cc] = v;
    }
    __syncthreads();
    float acc = 0.f;
    #pragma unroll 8
    for (int k = 0; k < D1; ++k)
        acc += As[r * 520 + k] * Ws[k * 16 + c];
    int gr = row0 + r;
    float ps = acc * as2v[c];
    float pd = acc * ad2v[c];
    #pragma unroll
    for (int off = 1; off < 16; off <<= 1) {
        ps += __shfl_xor(ps, off);
        pd += __shfl_xor(pd, off);
    }
    if (gr < N_NODES) {
        H2[gr * OUT_CH + c] = acc;
        if (c == 0) { a_src2[gr] = ps; a_dst2[gr] = pd; }
    }
}

// ---------------- layer-2 aggregation + bias + log_softmax ------------------
__global__ __launch_bounds__(256) void k_agg2(const float* __restrict__ H2,
                                              const float* __restrict__ a_src,
                                              const float* __restrict__ a_dst,
                                              const int* __restrict__ offsets,
                                              const int* __restrict__ csr,
                                              const float* __restrict__ b2,
                                              float* __restrict__ OUT) {
    int wave = (blockIdx.x * blockDim.x + threadIdx.x) >> 6;
    int lane = threadIdx.x & 63;
    if (wave >= N_NODES) return;
    int d = wave;
    int c = lane & 15;
    float ad = a_dst[d];
    float es = a_src[d] + ad;
    es = es > 0.f ? es : NEG_SLOPE * es;
    float m = es, lsum = 1.0f;
    float o = H2[d * OUT_CH + c];
    int beg = offsets[d], end = offsets[d + 1];
    for (int idx = beg; idx < end; ++idx) {
        int s = csr[idx];
        float e = a_src[s] + ad;
        e = e > 0.f ? e : NEG_SLOPE * e;
        float mnew = fmaxf(m, e);
        float scale = __expf(m - mnew);
        float w = __expf(e - mnew);
        lsum = lsum * scale + w;
        o = o * scale + w * H2[s * OUT_CH + c];
        m = mnew;
    }
    float v = o / (lsum + 1e-16f) + b2[c];
    float mx = v;
    #pragma unroll
    for (int off = 1; off < 16; off <<= 1) mx = fmaxf(mx, __shfl_xor(mx, off));
    float ex = __expf(v - mx);
    float se = ex;
    #pragma unroll
    for (int off = 1; off < 16; off <<= 1) se += __shfl_xor(se, off);
    float res = v - mx - logf(se);
    if (lane < 16) OUT[d * OUT_CH + lane] = res;
}

// ---------------- launcher --------------------------------------------------
extern "C" void kernel_launch(void* const* d_in, const int* in_sizes, int n_in,
                              void* d_out, int out_size, void* d_ws, size_t ws_size,
                              hipStream_t stream) {
    const float* x        = (const float*)d_in[0];
    const int*   ei       = (const int*)d_in[1];     // [2, E] int32 per harness convention
    const float* W1       = (const float*)d_in[2];
    const float* att_src1 = (const float*)d_in[3];
    const float* att_dst1 = (const float*)d_in[4];
    const float* b1       = (const float*)d_in[5];
    const float* W2       = (const float*)d_in[6];
    const float* att_src2 = (const float*)d_in[7];
    const float* att_dst2 = (const float*)d_in[8];
    const float* b2       = (const float*)d_in[9];
    float* out = (float*)d_out;

    const int* esrc = ei;
    const int* edst = ei + N_EDGES;

    // workspace carve-up (bytes)
    char* ws = (char*)d_ws;
    size_t off = 0;
    auto alloc = [&](size_t bytes) { char* p = ws + off; off = (off + bytes + 255) & ~(size_t)255; return p; };
    float* h1      = (float*)alloc((size_t)N_NODES * D1 * 4);      // 102.4 MB
    float* out1    = (float*)alloc((size_t)N_NODES * D1 * 4);      // 102.4 MB
    float* a_src1  = (float*)alloc((size_t)N_NODES * HEADS * 4);
    float* a_dst1  = (float*)alloc((size_t)N_NODES * HEADS * 4);
    float* h2      = (float*)alloc((size_t)N_NODES * OUT_CH * 4);
    float* a_src2  = (float*)alloc((size_t)N_NODES * 4);
    float* a_dst2  = (float*)alloc((size_t)N_NODES * 4);
    int*   deg     = (int*)alloc((size_t)N_NODES * 4);
    int*   offsets = (int*)alloc((size_t)(N_NODES + 1) * 4);
    int*   cursor  = (int*)alloc((size_t)N_NODES * 4);
    int*   csr     = (int*)alloc((size_t)N_EDGES * 4);
    (void)ws_size;

    // 1. GEMM1
    dim3 g1((N_NODES + 63) / 64, D1 / 64);
    k_gemm1<<<g1, 256, 0, stream>>>(x, W1, h1);
    // 2. attention logits layer 1
    k_att1<<<(N_NODES * 64 + 255) / 256, 256, 0, stream>>>(h1, att_src1, att_dst1, a_src1, a_dst1);
    // 3. CSR build
    k_zero<<<(N_NODES + 255) / 256, 256, 0, stream>>>(deg);
    k_hist<<<(N_EDGES + 255) / 256, 256, 0, stream>>>(edst, deg);
    k_scan<<<1, 1024, 0, stream>>>(deg, offsets);
    k_copy<<<(N_NODES + 255) / 256, 256, 0, stream>>>(offsets, cursor);
    k_scatter<<<(N_EDGES + 255) / 256, 256, 0, stream>>>(esrc, edst, cursor, csr);
    // 4. layer-1 aggregation (+bias+ELU)
    k_agg1<<<(N_NODES * 64 + 255) / 256, 256, 0, stream>>>(h1, a_src1, a_dst1, offsets, csr, b1, out1);
    // 5. GEMM2 + layer-2 logits
    k_gemm2<<<(N_NODES + 15) / 16, 256, 0, stream>>>(out1, W2, att_src2, att_dst2, h2, a_src2, a_dst2);
    // 6. layer-2 aggregation + bias + log_softmax
    k_agg2<<<(N_NODES * 64 + 255) / 256, 256, 0, stream>>>(h2, a_src2, a_dst2, offsets, csr, b2, out);
}

// Round 2
// 545.859 us; speedup vs baseline: 1.2982x; 1.2982x over previous
//
#include <hip/hip_runtime.h>
#include <math.h>

#define N_NODES 50000
#define N_EDGES 500000
#define IN_CH 256
#define D1 512          // HEADS*HID
#define HEADS 8
#define HID 64
#define OUT_CH 16
#define NEG_SLOPE 0.2f

typedef __bf16 bf16x8 __attribute__((ext_vector_type(8)));
typedef float f32x4 __attribute__((ext_vector_type(4)));

// ---------------- fp32 -> bf16 converts -------------------------------------
__global__ __launch_bounds__(256) void k_cvt_x(const float* __restrict__ X,
                                               __bf16* __restrict__ Xb) {
    size_t i = ((size_t)blockIdx.x * 256 + threadIdx.x) * 8;   // exact multiple
    float4 v0 = *(const float4*)&X[i];
    float4 v1 = *(const float4*)&X[i + 4];
    __bf16 o[8] = {(__bf16)v0.x, (__bf16)v0.y, (__bf16)v0.z, (__bf16)v0.w,
                   (__bf16)v1.x, (__bf16)v1.y, (__bf16)v1.z, (__bf16)v1.w};
    *(uint4*)&Xb[i] = *(uint4*)o;
}

// W1 [256,512] fp32 -> Wt [512,256] bf16 (transposed)
__global__ __launch_bounds__(256) void k_cvt_w1(const float* __restrict__ W,
                                                __bf16* __restrict__ Wt) {
    int idx = blockIdx.x * 256 + threadIdx.x;     // 0..131071
    int n = idx >> 8;
    int k = idx & 255;
    Wt[idx] = (__bf16)W[k * D1 + n];
}

// ---------------- GEMM1 (MFMA): h1[N,512] = Xb[N,256] @ Wt^T ----------------
// Xb row-major [M,256]; Wt row-major [512,256] (i.e. B^T). 128x128 tile, BK=32.
__global__ __launch_bounds__(256) void k_gemm1_mfma(const __bf16* __restrict__ Xb,
                                                    const __bf16* __restrict__ Wt,
                                                    float* __restrict__ H) {
    __shared__ __bf16 As[128][40];   // pad 32->40 to break bank conflicts
    __shared__ __bf16 Bs[128][40];
    int tid = threadIdx.x;
    int wid = tid >> 6, lane = tid & 63;
    int wr = wid >> 1, wc = wid & 1;           // 2x2 waves of 64x64
    int row0 = blockIdx.x * 128;
    int col0 = blockIdx.y * 128;
    int lq = lane >> 4;                        // 0..3
    int lm = lane & 15;
    f32x4 acc[4][4] = {};
    for (int k0 = 0; k0 < IN_CH; k0 += 32) {
        #pragma unroll
        for (int it = 0; it < 2; ++it) {
            int idx = tid + it * 256;          // 0..511
            int r  = idx >> 2;                 // 0..127
            int c8 = (idx & 3) * 8;            // 0,8,16,24
            int gr = row0 + r;
            uint4 va = (gr < N_NODES) ? *(const uint4*)&Xb[(size_t)gr * IN_CH + k0 + c8]
                                      : make_uint4(0u, 0u, 0u, 0u);
            *(uint4*)&As[r][c8] = va;
            uint4 vb = *(const uint4*)&Wt[(size_t)(col0 + r) * IN_CH + k0 + c8];
            *(uint4*)&Bs[r][c8] = vb;
        }
        __syncthreads();
        bf16x8 af[4], bfr[4];
        #pragma unroll
        for (int i = 0; i < 4; ++i) af[i]  = *(bf16x8*)&As[wr * 64 + i * 16 + lm][lq * 8];
        #pragma unroll
        for (int j = 0; j < 4; ++j) bfr[j] = *(bf16x8*)&Bs[wc * 64 + j * 16 + lm][lq * 8];
        #pragma unroll
        for (int i = 0; i < 4; ++i)
            #pragma unroll
            for (int j = 0; j < 4; ++j)
                acc[i][j] = __builtin_amdgcn_mfma_f32_16x16x32_bf16(af[i], bfr[j], acc[i][j], 0, 0, 0);
        __syncthreads();
    }
    // epilogue: C/D layout col=lane&15, row=(lane>>4)*4+reg
    #pragma unroll
    for (int i = 0; i < 4; ++i) {
        int rbase = row0 + wr * 64 + i * 16 + lq * 4;
        #pragma unroll
        for (int j = 0; j < 4; ++j) {
            int gcol = col0 + wc * 64 + j * 16 + lm;
            #pragma unroll
            for (int r = 0; r < 4; ++r) {
                int grow = rbase + r;
                if (grow < N_NODES) H[(size_t)grow * D1 + gcol] = acc[i][j][r];
            }
        }
    }
}

// ---------------- per-node attention logits layer 1: a_src/a_dst [N,8] ------
__global__ __launch_bounds__(256) void k_att1(const float* __restrict__ H,
                                              const float* __restrict__ att_src,
                                              const float* __restrict__ att_dst,
                                              float* __restrict__ a_src,
                                              float* __restrict__ a_dst) {
    int wave = (blockIdx.x * blockDim.x + threadIdx.x) >> 6;
    int lane = threadIdx.x & 63;
    if (wave >= N_NODES) return;
    const float* hrow = H + (size_t)wave * D1 + lane * 8;
    float4 h0 = *(const float4*)hrow;
    float4 h1 = *(const float4*)(hrow + 4);
    float4 s0 = *(const float4*)&att_src[lane * 8];
    float4 s1 = *(const float4*)&att_src[lane * 8 + 4];
    float4 d0 = *(const float4*)&att_dst[lane * 8];
    float4 d1 = *(const float4*)&att_dst[lane * 8 + 4];
    float ps = h0.x * s0.x + h0.y * s0.y + h0.z * s0.z + h0.w * s0.w
             + h1.x * s1.x + h1.y * s1.y + h1.z * s1.z + h1.w * s1.w;
    float pd = h0.x * d0.x + h0.y * d0.y + h0.z * d0.z + h0.w * d0.w
             + h1.x * d1.x + h1.y * d1.y + h1.z * d1.z + h1.w * d1.w;
    #pragma unroll
    for (int off = 1; off < 8; off <<= 1) {
        ps += __shfl_xor(ps, off);
        pd += __shfl_xor(pd, off);
    }
    if ((lane & 7) == 0) {
        a_src[wave * HEADS + (lane >> 3)] = ps;
        a_dst[wave * HEADS + (lane >> 3)] = pd;
    }
}

// ---------------- CSR build ------------------------------------------------
__global__ void k_zero(int* __restrict__ deg) {
    int i = blockIdx.x * blockDim.x + threadIdx.x;
    if (i < N_NODES) deg[i] = 0;
}

__global__ void k_hist(const int* __restrict__ dst, int* __restrict__ deg) {
    int e = blockIdx.x * blockDim.x + threadIdx.x;
    if (e < N_EDGES) atomicAdd(&deg[dst[e]], 1);
}

// shuffle-based single-block scan (2-3 barriers per 1024-tile vs 20 before)
__global__ __launch_bounds__(1024) void k_scan(const int* __restrict__ deg,
                                               int* __restrict__ offsets) {
    __shared__ int wsum[16];
    __shared__ int carry_s;
    int tid = threadIdx.x, lane = tid & 63, wid = tid >> 6;
    if (tid == 0) carry_s = 0;
    __syncthreads();
    for (int base = 0; base < N_NODES; base += 1024) {
        int i = base + tid;
        int v = (i < N_NODES) ? deg[i] : 0;
        int x = v;
        #pragma unroll
        for (int off = 1; off < 64; off <<= 1) {
            int t = __shfl_up(x, off);
            if (lane >= off) x += t;
        }
        if (lane == 63) wsum[wid] = x;
        __syncthreads();
        if (wid == 0) {
            int s = (lane < 16) ? wsum[lane] : 0;
            #pragma unroll
            for (int off = 1; off < 16; off <<= 1) {
                int t = __shfl_up(s, off);
                if (lane >= off) s += t;
            }
            if (lane < 16) wsum[lane] = s;   // inclusive scan of wave sums
        }
        __syncthreads();
        int wbase = (wid == 0) ? 0 : wsum[wid - 1];
        int c = carry_s;
        if (i < N_NODES) offsets[i] = c + wbase + x - v;   // exclusive
        __syncthreads();
        if (tid == 1023) carry_s = c + wsum[15];
        __syncthreads();
    }
    if (threadIdx.x == 0) offsets[N_NODES] = carry_s;
}

__global__ void k_copy(const int* __restrict__ src, int* __restrict__ dstp) {
    int i = blockIdx.x * blockDim.x + threadIdx.x;
    if (i < N_NODES) dstp[i] = src[i];
}

__global__ void k_scatter(const int* __restrict__ esrc, const int* __restrict__ edst,
                          int* __restrict__ cursor, int* __restrict__ csr) {
    int e = blockIdx.x * blockDim.x + threadIdx.x;
    if (e < N_EDGES) {
        int d = edst[e];
        int pos = atomicAdd(&cursor[d], 1);
        csr[pos] = esrc[e];
    }
}

// ---------------- layer-1 aggregation: online softmax, wave per node --------
__global__ __launch_bounds__(256) void k_agg1(const float* __restrict__ H,
                                              const float* __restrict__ a_src,
                                              const float* __restrict__ a_dst,
                                              const int* __restrict__ offsets,
                                              const int* __restrict__ csr,
                                              const float* __restrict__ b1,
                                              float* __restrict__ OUT) {
    int wave = (blockIdx.x * blockDim.x + threadIdx.x) >> 6;
    int lane = threadIdx.x & 63;
    if (wave >= N_NODES) return;
    int d = wave;
    int head = lane >> 3;
    float ad = a_dst[d * HEADS + head];
    float es = a_src[d * HEADS + head] + ad;   // self-loop seed
    es = es > 0.f ? es : NEG_SLOPE * es;
    const float* hrow = H + (size_t)d * D1 + lane * 8;
    float4 t0 = *(const float4*)hrow;
    float4 t1 = *(const float4*)(hrow + 4);
    float o[8] = {t0.x, t0.y, t0.z, t0.w, t1.x, t1.y, t1.z, t1.w};
    float m = es, lsum = 1.0f;
    int beg = offsets[d], end = offsets[d + 1];
    for (int idx = beg; idx < end; ++idx) {
        int s = csr[idx];
        float e = a_src[s * HEADS + head] + ad;
        e = e > 0.f ? e : NEG_SLOPE * e;
        float mnew = fmaxf(m, e);
        float scale = __expf(m - mnew);
        float w = __expf(e - mnew);
        const float* hs = H + (size_t)s * D1 + lane * 8;
        float4 u0 = *(const float4*)hs;
        float4 u1 = *(const float4*)(hs + 4);
        lsum = lsum * scale + w;
        o[0] = o[0] * scale + w * u0.x; o[1] = o[1] * scale + w * u0.y;
        o[2] = o[2] * scale + w * u0.z; o[3] = o[3] * scale + w * u0.w;
        o[4] = o[4] * scale + w * u1.x; o[5] = o[5] * scale + w * u1.y;
        o[6] = o[6] * scale + w * u1.z; o[7] = o[7] * scale + w * u1.w;
        m = mnew;
    }
    float inv = 1.0f / (lsum + 1e-16f);
    float r[8];
    #pragma unroll
    for (int j = 0; j < 8; ++j) {
        float v = o[j] * inv + b1[lane * 8 + j];
        r[j] = v > 0.f ? v : expm1f(v);     // ELU
    }
    float* orow = OUT + (size_t)d * D1 + lane * 8;
    *(float4*)orow       = make_float4(r[0], r[1], r[2], r[3]);
    *(float4*)(orow + 4) = make_float4(r[4], r[5], r[6], r[7]);
}

// ---------------- GEMM2 + layer-2 attention logits -------------------------
__global__ __launch_bounds__(256) void k_gemm2(const float* __restrict__ A,
                                               const float* __restrict__ W,
                                               const float* __restrict__ as2v,
                                               const float* __restrict__ ad2v,
                                               float* __restrict__ H2,
                                               float* __restrict__ a_src2,
                                               float* __restrict__ a_dst2) {
    __shared__ float As[16 * 520];     // 16 rows, stride 520 (pad 8)
    __shared__ float Ws[512 * 16];
    int tid = threadIdx.x;
    int r = tid >> 4, c = tid & 15;
    int row0 = blockIdx.x * 16;
    #pragma unroll
    for (int i = 0; i < 8; ++i) {      // W2: 8192 floats
        int q = tid + i * 256;
        *(float4*)&Ws[q * 4] = *(const float4*)&W[q * 4];
    }
    #pragma unroll
    for (int i = 0; i < 8; ++i) {      // A tile: 16x512
        int q = tid + i * 256;
        int rr = q >> 7;
        int cc = (q & 127) * 4;
        int gr = row0 + rr;
        float4 v = (gr < N_NODES) ? *(const float4*)&A[(size_t)gr * D1 + cc]
                                  : make_float4(0.f, 0.f, 0.f, 0.f);
        *(float4*)&As[rr * 520 + cc] = v;
    }
    __syncthreads();
    float acc = 0.f;
    #pragma unroll 8
    for (int k = 0; k < D1; ++k)
        acc += As[r * 520 + k] * Ws[k * 16 + c];
    int gr = row0 + r;
    float ps = acc * as2v[c];
    float pd = acc * ad2v[c];
    #pragma unroll
    for (int off = 1; off < 16; off <<= 1) {
        ps += __shfl_xor(ps, off);
        pd += __shfl_xor(pd, off);
    }
    if (gr < N_NODES) {
        H2[gr * OUT_CH + c] = acc;
        if (c == 0) { a_src2[gr] = ps; a_dst2[gr] = pd; }
    }
}

// ---------------- layer-2 aggregation + bias + log_softmax ------------------
__global__ __launch_bounds__(256) void k_agg2(const float* __restrict__ H2,
                                              const float* __restrict__ a_src,
                                              const float* __restrict__ a_dst,
                                              const int* __restrict__ offsets,
                                              const int* __restrict__ csr,
                                              const float* __restrict__ b2,
                                              float* __restrict__ OUT) {
    int wave = (blockIdx.x * blockDim.x + threadIdx.x) >> 6;
    int lane = threadIdx.x & 63;
    if (wave >= N_NODES) return;
    int d = wave;
    int c = lane & 15;
    float ad = a_dst[d];
    float es = a_src[d] + ad;
    es = es > 0.f ? es : NEG_SLOPE * es;
    float m = es, lsum = 1.0f;
    float o = H2[d * OUT_CH + c];
    int beg = offsets[d], end = offsets[d + 1];
    for (int idx = beg; idx < end; ++idx) {
        int s = csr[idx];
        float e = a_src[s] + ad;
        e = e > 0.f ? e : NEG_SLOPE * e;
        float mnew = fmaxf(m, e);
        float scale = __expf(m - mnew);
        float w = __expf(e - mnew);
        lsum = lsum * scale + w;
        o = o * scale + w * H2[s * OUT_CH + c];
        m = mnew;
    }
    float v = o / (lsum + 1e-16f) + b2[c];
    float mx = v;
    #pragma unroll
    for (int off = 1; off < 16; off <<= 1) mx = fmaxf(mx, __shfl_xor(mx, off));
    float ex = __expf(v - mx);
    float se = ex;
    #pragma unroll
    for (int off = 1; off < 16; off <<= 1) se += __shfl_xor(se, off);
    float res = v - mx - logf(se);
    if (lane < 16) OUT[d * OUT_CH + lane] = res;
}

// ---------------- launcher --------------------------------------------------
extern "C" void kernel_launch(void* const* d_in, const int* in_sizes, int n_in,
                              void* d_out, int out_size, void* d_ws, size_t ws_size,
                              hipStream_t stream) {
    const float* x        = (const float*)d_in[0];
    const int*   ei       = (const int*)d_in[1];
    const float* W1       = (const float*)d_in[2];
    const float* att_src1 = (const float*)d_in[3];
    const float* att_dst1 = (const float*)d_in[4];
    const float* b1       = (const float*)d_in[5];
    const float* W2       = (const float*)d_in[6];
    const float* att_src2 = (const float*)d_in[7];
    const float* att_dst2 = (const float*)d_in[8];
    const float* b2       = (const float*)d_in[9];
    float* out = (float*)d_out;

    const int* esrc = ei;
    const int* edst = ei + N_EDGES;

    char* ws = (char*)d_ws;
    size_t off = 0;
    auto alloc = [&](size_t bytes) { char* p = ws + off; off = (off + bytes + 255) & ~(size_t)255; return p; };
    float* h1      = (float*)alloc((size_t)N_NODES * D1 * 4);      // 102.4 MB
    float* out1    = (float*)alloc((size_t)N_NODES * D1 * 4);      // 102.4 MB
    float* a_src1  = (float*)alloc((size_t)N_NODES * HEADS * 4);
    float* a_dst1  = (float*)alloc((size_t)N_NODES * HEADS * 4);
    float* h2      = (float*)alloc((size_t)N_NODES * OUT_CH * 4);
    float* a_src2  = (float*)alloc((size_t)N_NODES * 4);
    float* a_dst2  = (float*)alloc((size_t)N_NODES * 4);
    int*   deg     = (int*)alloc((size_t)N_NODES * 4);
    int*   offsets = (int*)alloc((size_t)(N_NODES + 1) * 4);
    int*   cursor  = (int*)alloc((size_t)N_NODES * 4);
    int*   csr     = (int*)alloc((size_t)N_EDGES * 4);
    (void)ws_size;

    // Xb/Wt live inside out1's region: consumed by gemm1 before k_agg1 overwrites out1
    __bf16* Xb = (__bf16*)out1;                                   // 25.6 MB
    __bf16* Wt = (__bf16*)(out1 + 8 * 1024 * 1024);               // at +32 MB, 0.26 MB

    // 0. converts
    k_cvt_x<<<(N_NODES * IN_CH / 8 + 255) / 256, 256, 0, stream>>>(x, Xb);
    k_cvt_w1<<<(D1 * IN_CH + 255) / 256, 256, 0, stream>>>(W1, Wt);
    // 1. GEMM1 (MFMA)
    dim3 g1((N_NODES + 127) / 128, D1 / 128);
    k_gemm1_mfma<<<g1, 256, 0, stream>>>(Xb, Wt, h1);
    // 2. attention logits layer 1
    k_att1<<<(N_NODES * 64 + 255) / 256, 256, 0, stream>>>(h1, att_src1, att_dst1, a_src1, a_dst1);
    // 3. CSR build
    k_zero<<<(N_NODES + 255) / 256, 256, 0, stream>>>(deg);
    k_hist<<<(N_EDGES + 255) / 256, 256, 0, stream>>>(edst, deg);
    k_scan<<<1, 1024, 0, stream>>>(deg, offsets);
    k_copy<<<(N_NODES + 255) / 256, 256, 0, stream>>>(offsets, cursor);
    k_scatter<<<(N_EDGES + 255) / 256, 256, 0, stream>>>(esrc, edst, cursor, csr);
    // 4. layer-1 aggregation (+bias+ELU)
    k_agg1<<<(N_NODES * 64 + 255) / 256, 256, 0, stream>>>(h1, a_src1, a_dst1, offsets, csr, b1, out1);
    // 5. GEMM2 + layer-2 logits
    k_gemm2<<<(N_NODES + 15) / 16, 256, 0, stream>>>(out1, W2, att_src2, att_dst2, h2, a_src2, a_dst2);
    // 6. layer-2 aggregation + bias + log_softmax
    k_agg2<<<(N_NODES * 64 + 255) / 256, 256, 0, stream>>>(h2, a_src2, a_dst2, offsets, csr, b2, out);
}

// Round 3
// 407.715 us; speedup vs baseline: 1.7380x; 1.3388x over previous
//
#include <hip/hip_runtime.h>
#include <math.h>

#define N_NODES 50000
#define N_EDGES 500000
#define IN_CH 256
#define D1 512          // HEADS*HID
#define HEADS 8
#define HID 64
#define OUT_CH 16
#define NEG_SLOPE 0.2f

typedef __bf16 bf16x8 __attribute__((ext_vector_type(8)));
typedef float f32x4 __attribute__((ext_vector_type(4)));

// ---------------- fp32 -> bf16 converts -------------------------------------
__global__ __launch_bounds__(256) void k_cvt_x(const float* __restrict__ X,
                                               __bf16* __restrict__ Xb) {
    size_t i = ((size_t)blockIdx.x * 256 + threadIdx.x) * 8;   // exact multiple
    float4 v0 = *(const float4*)&X[i];
    float4 v1 = *(const float4*)&X[i + 4];
    __bf16 o[8] = {(__bf16)v0.x, (__bf16)v0.y, (__bf16)v0.z, (__bf16)v0.w,
                   (__bf16)v1.x, (__bf16)v1.y, (__bf16)v1.z, (__bf16)v1.w};
    *(uint4*)&Xb[i] = *(uint4*)o;
}

// W1 [256,512] fp32 -> Wt [512,256] bf16 (transposed)
__global__ __launch_bounds__(256) void k_cvt_w1(const float* __restrict__ W,
                                                __bf16* __restrict__ Wt) {
    int idx = blockIdx.x * 256 + threadIdx.x;     // 0..131071
    int n = idx >> 8;
    int k = idx & 255;
    Wt[idx] = (__bf16)W[k * D1 + n];
}

// ---------------- GEMM1 (MFMA) + fused att1 logits --------------------------
// Hb[N,512] bf16 = Xb[N,256] @ Wt^T; a_src/a_dst[N,8] from acc registers.
// Each wave's 64-col span == one head (cols col0+wc*64 .. +63).
__global__ __launch_bounds__(256) void k_gemm1_mfma(const __bf16* __restrict__ Xb,
                                                    const __bf16* __restrict__ Wt,
                                                    const float* __restrict__ att_src,
                                                    const float* __restrict__ att_dst,
                                                    __bf16* __restrict__ Hb,
                                                    float* __restrict__ a_src1,
                                                    float* __restrict__ a_dst1) {
    __shared__ __bf16 As[128][40];   // pad 32->40 to break bank conflicts
    __shared__ __bf16 Bs[128][40];
    int tid = threadIdx.x;
    int wid = tid >> 6, lane = tid & 63;
    int wr = wid >> 1, wc = wid & 1;           // 2x2 waves of 64x64
    int row0 = blockIdx.x * 128;
    int col0 = blockIdx.y * 128;
    int lq = lane >> 4;                        // 0..3
    int lm = lane & 15;
    f32x4 acc[4][4] = {};
    for (int k0 = 0; k0 < IN_CH; k0 += 32) {
        #pragma unroll
        for (int it = 0; it < 2; ++it) {
            int idx = tid + it * 256;          // 0..511
            int r  = idx >> 2;                 // 0..127
            int c8 = (idx & 3) * 8;            // 0,8,16,24
            int gr = row0 + r;
            uint4 va = (gr < N_NODES) ? *(const uint4*)&Xb[(size_t)gr * IN_CH + k0 + c8]
                                      : make_uint4(0u, 0u, 0u, 0u);
            *(uint4*)&As[r][c8] = va;
            uint4 vb = *(const uint4*)&Wt[(size_t)(col0 + r) * IN_CH + k0 + c8];
            *(uint4*)&Bs[r][c8] = vb;
        }
        __syncthreads();
        bf16x8 af[4], bfr[4];
        #pragma unroll
        for (int i = 0; i < 4; ++i) af[i]  = *(bf16x8*)&As[wr * 64 + i * 16 + lm][lq * 8];
        #pragma unroll
        for (int j = 0; j < 4; ++j) bfr[j] = *(bf16x8*)&Bs[wc * 64 + j * 16 + lm][lq * 8];
        #pragma unroll
        for (int i = 0; i < 4; ++i)
            #pragma unroll
            for (int j = 0; j < 4; ++j)
                acc[i][j] = __builtin_amdgcn_mfma_f32_16x16x32_bf16(af[i], bfr[j], acc[i][j], 0, 0, 0);
        __syncthreads();
    }
    // ---- epilogue: store bf16 H + fused per-head attention dots ----
    int head = blockIdx.y * 2 + wc;            // this wave's head
    float as_v[4], ad_v[4];
    #pragma unroll
    for (int j = 0; j < 4; ++j) {
        as_v[j] = att_src[head * HID + j * 16 + lm];
        ad_v[j] = att_dst[head * HID + j * 16 + lm];
    }
    #pragma unroll
    for (int i = 0; i < 4; ++i) {
        int rbase = row0 + wr * 64 + i * 16 + lq * 4;
        #pragma unroll
        for (int r = 0; r < 4; ++r) {
            int grow = rbase + r;
            float ps = 0.f, pd = 0.f;
            #pragma unroll
            for (int j = 0; j < 4; ++j) {
                float v = acc[i][j][r];
                ps += v * as_v[j];
                pd += v * ad_v[j];
                if (grow < N_NODES)
                    Hb[(size_t)grow * D1 + col0 + wc * 64 + j * 16 + lm] = (__bf16)v;
            }
            #pragma unroll
            for (int off = 1; off < 16; off <<= 1) {
                ps += __shfl_xor(ps, off);
                pd += __shfl_xor(pd, off);
            }
            if (lm == 0 && grow < N_NODES) {
                a_src1[grow * HEADS + head] = ps;
                a_dst1[grow * HEADS + head] = pd;
            }
        }
    }
}

// ---------------- CSR build ------------------------------------------------
__global__ void k_zero(int* __restrict__ deg) {
    int i = blockIdx.x * blockDim.x + threadIdx.x;
    if (i < N_NODES) deg[i] = 0;
}

__global__ void k_hist(const int* __restrict__ dst, int* __restrict__ deg) {
    int e = blockIdx.x * blockDim.x + threadIdx.x;
    if (e < N_EDGES) atomicAdd(&deg[dst[e]], 1);
}

// multi-block scan phase 1: per-block exclusive scan + block sums
__global__ __launch_bounds__(1024) void k_scan1(const int* __restrict__ deg,
                                                int* __restrict__ offsets,
                                                int* __restrict__ bsum) {
    __shared__ int wsum[16];
    int tid = threadIdx.x, lane = tid & 63, wid = tid >> 6;
    int i = blockIdx.x * 1024 + tid;
    int v = (i < N_NODES) ? deg[i] : 0;
    int x = v;
    #pragma unroll
    for (int off = 1; off < 64; off <<= 1) {
        int t = __shfl_up(x, off);
        if (lane >= off) x += t;
    }
    if (lane == 63) wsum[wid] = x;
    __syncthreads();
    if (wid == 0) {
        int s = (lane < 16) ? wsum[lane] : 0;
        #pragma unroll
        for (int off = 1; off < 16; off <<= 1) {
            int t = __shfl_up(s, off);
            if (lane >= off) s += t;
        }
        if (lane < 16) wsum[lane] = s;
    }
    __syncthreads();
    int wbase = wid ? wsum[wid - 1] : 0;
    if (i < N_NODES) offsets[i] = wbase + x - v;
    if (tid == 1023) bsum[blockIdx.x] = wsum[15];
}

// phase 2: single 64-thread block scans block sums (nb <= 64)
__global__ __launch_bounds__(64) void k_scan2(const int* __restrict__ bsum,
                                              int* __restrict__ bpre,
                                              int* __restrict__ offsets) {
    int tid = threadIdx.x;
    int nb = (N_NODES + 1023) / 1024;
    int v = (tid < nb) ? bsum[tid] : 0;
    int x = v;
    #pragma unroll
    for (int off = 1; off < 64; off <<= 1) {
        int t = __shfl_up(x, off);
        if (tid >= off) x += t;
    }
    if (tid < nb) bpre[tid] = x - v;
    if (tid == 63) offsets[N_NODES] = x;   // grand total
}

// phase 3: add block prefixes; also fill cursor
__global__ void k_scan3(int* __restrict__ offsets, const int* __restrict__ bpre,
                        int* __restrict__ cursor) {
    int i = blockIdx.x * blockDim.x + threadIdx.x;
    if (i < N_NODES) {
        int o = offsets[i] + bpre[i >> 10];
        offsets[i] = o;
        cursor[i] = o;
    }
}

__global__ void k_scatter(const int* __restrict__ esrc, const int* __restrict__ edst,
                          int* __restrict__ cursor, int* __restrict__ csr) {
    int e = blockIdx.x * blockDim.x + threadIdx.x;
    if (e < N_EDGES) {
        int d = edst[e];
        int pos = atomicAdd(&cursor[d], 1);
        csr[pos] = esrc[e];
    }
}

// ---------------- layer-1 aggregation: online softmax, wave per node --------
// bf16 gather, fp32 accumulate, pairwise edge processing, bf16 output (+ELU)
__global__ __launch_bounds__(256) void k_agg1(const __bf16* __restrict__ Hb,
                                              const float* __restrict__ a_src,
                                              const float* __restrict__ a_dst,
                                              const int* __restrict__ offsets,
                                              const int* __restrict__ csr,
                                              const float* __restrict__ b1,
                                              __bf16* __restrict__ OUT) {
    int wave = (blockIdx.x * blockDim.x + threadIdx.x) >> 6;
    int lane = threadIdx.x & 63;
    if (wave >= N_NODES) return;
    int d = wave;
    int head = lane >> 3;
    float ad = a_dst[d * HEADS + head];
    float es = a_src[d * HEADS + head] + ad;   // self-loop seed
    es = es > 0.f ? es : NEG_SLOPE * es;
    bf16x8 hs = *(const bf16x8*)&Hb[(size_t)d * D1 + lane * 8];
    float o[8];
    #pragma unroll
    for (int j = 0; j < 8; ++j) o[j] = (float)hs[j];
    float m = es, lsum = 1.0f;
    int beg = offsets[d], end = offsets[d + 1];
    int idx = beg;
    for (; idx + 2 <= end; idx += 2) {
        int s1 = csr[idx], s2 = csr[idx + 1];
        float f1 = a_src[s1 * HEADS + head] + ad;
        float f2 = a_src[s2 * HEADS + head] + ad;
        f1 = f1 > 0.f ? f1 : NEG_SLOPE * f1;
        f2 = f2 > 0.f ? f2 : NEG_SLOPE * f2;
        bf16x8 u1 = *(const bf16x8*)&Hb[(size_t)s1 * D1 + lane * 8];
        bf16x8 u2 = *(const bf16x8*)&Hb[(size_t)s2 * D1 + lane * 8];
        float mnew = fmaxf(m, fmaxf(f1, f2));
        float scale = __expf(m - mnew);
        float w1 = __expf(f1 - mnew);
        float w2 = __expf(f2 - mnew);
        lsum = lsum * scale + w1 + w2;
        #pragma unroll
        for (int j = 0; j < 8; ++j)
            o[j] = o[j] * scale + w1 * (float)u1[j] + w2 * (float)u2[j];
        m = mnew;
    }
    if (idx < end) {
        int s = csr[idx];
        float e = a_src[s * HEADS + head] + ad;
        e = e > 0.f ? e : NEG_SLOPE * e;
        float mnew = fmaxf(m, e);
        float scale = __expf(m - mnew);
        float w = __expf(e - mnew);
        bf16x8 u = *(const bf16x8*)&Hb[(size_t)s * D1 + lane * 8];
        lsum = lsum * scale + w;
        #pragma unroll
        for (int j = 0; j < 8; ++j) o[j] = o[j] * scale + w * (float)u[j];
        m = mnew;
    }
    float inv = 1.0f / (lsum + 1e-16f);
    __bf16 r[8];
    #pragma unroll
    for (int j = 0; j < 8; ++j) {
        float v = o[j] * inv + b1[lane * 8 + j];
        v = v > 0.f ? v : expm1f(v);     // ELU
        r[j] = (__bf16)v;
    }
    *(uint4*)&OUT[(size_t)d * D1 + lane * 8] = *(uint4*)r;
}

// ---------------- GEMM2 (bf16 A) + layer-2 attention logits -----------------
__global__ __launch_bounds__(256) void k_gemm2(const __bf16* __restrict__ A,
                                               const float* __restrict__ W,
                                               const float* __restrict__ as2v,
                                               const float* __restrict__ ad2v,
                                               float* __restrict__ H2,
                                               float* __restrict__ a_src2,
                                               float* __restrict__ a_dst2) {
    __shared__ __bf16 As[16][520];     // pad 512->520 (stride 1040B: 2-way = free)
    __shared__ float Ws[512 * 16];
    int tid = threadIdx.x;
    int r = tid >> 4, c = tid & 15;
    int row0 = blockIdx.x * 16;
    #pragma unroll
    for (int i = 0; i < 8; ++i) {      // W2: 8192 floats
        int q = tid + i * 256;
        *(float4*)&Ws[q * 4] = *(const float4*)&W[q * 4];
    }
    #pragma unroll
    for (int i = 0; i < 4; ++i) {      // A tile: 16x512 bf16 = 1024 x 8-elem
        int q = tid + i * 256;
        int rr = q >> 6;
        int cc = (q & 63) * 8;
        int gr = row0 + rr;
        uint4 v = (gr < N_NODES) ? *(const uint4*)&A[(size_t)gr * D1 + cc]
                                 : make_uint4(0u, 0u, 0u, 0u);
        *(uint4*)&As[rr][cc] = v;
    }
    __syncthreads();
    float acc = 0.f;
    #pragma unroll 8
    for (int k = 0; k < D1; ++k)
        acc += (float)As[r][k] * Ws[k * 16 + c];
    int gr = row0 + r;
    float ps = acc * as2v[c];
    float pd = acc * ad2v[c];
    #pragma unroll
    for (int off = 1; off < 16; off <<= 1) {
        ps += __shfl_xor(ps, off);
        pd += __shfl_xor(pd, off);
    }
    if (gr < N_NODES) {
        H2[gr * OUT_CH + c] = acc;
        if (c == 0) { a_src2[gr] = ps; a_dst2[gr] = pd; }
    }
}

// ---------------- layer-2 aggregation + bias + log_softmax ------------------
__global__ __launch_bounds__(256) void k_agg2(const float* __restrict__ H2,
                                              const float* __restrict__ a_src,
                                              const float* __restrict__ a_dst,
                                              const int* __restrict__ offsets,
                                              const int* __restrict__ csr,
                                              const float* __restrict__ b2,
                                              float* __restrict__ OUT) {
    int wave = (blockIdx.x * blockDim.x + threadIdx.x) >> 6;
    int lane = threadIdx.x & 63;
    if (wave >= N_NODES) return;
    int d = wave;
    int c = lane & 15;
    float ad = a_dst[d];
    float es = a_src[d] + ad;
    es = es > 0.f ? es : NEG_SLOPE * es;
    float m = es, lsum = 1.0f;
    float o = H2[d * OUT_CH + c];
    int beg = offsets[d], end = offsets[d + 1];
    for (int idx = beg; idx < end; ++idx) {
        int s = csr[idx];
        float e = a_src[s] + ad;
        e = e > 0.f ? e : NEG_SLOPE * e;
        float mnew = fmaxf(m, e);
        float scale = __expf(m - mnew);
        float w = __expf(e - mnew);
        lsum = lsum * scale + w;
        o = o * scale + w * H2[s * OUT_CH + c];
        m = mnew;
    }
    float v = o / (lsum + 1e-16f) + b2[c];
    float mx = v;
    #pragma unroll
    for (int off = 1; off < 16; off <<= 1) mx = fmaxf(mx, __shfl_xor(mx, off));
    float ex = __expf(v - mx);
    float se = ex;
    #pragma unroll
    for (int off = 1; off < 16; off <<= 1) se += __shfl_xor(se, off);
    float res = v - mx - logf(se);
    if (lane < 16) OUT[d * OUT_CH + lane] = res;
}

// ---------------- launcher --------------------------------------------------
extern "C" void kernel_launch(void* const* d_in, const int* in_sizes, int n_in,
                              void* d_out, int out_size, void* d_ws, size_t ws_size,
                              hipStream_t stream) {
    const float* x        = (const float*)d_in[0];
    const int*   ei       = (const int*)d_in[1];
    const float* W1       = (const float*)d_in[2];
    const float* att_src1 = (const float*)d_in[3];
    const float* att_dst1 = (const float*)d_in[4];
    const float* b1       = (const float*)d_in[5];
    const float* W2       = (const float*)d_in[6];
    const float* att_src2 = (const float*)d_in[7];
    const float* att_dst2 = (const float*)d_in[8];
    const float* b2       = (const float*)d_in[9];
    float* out = (float*)d_out;

    const int* esrc = ei;
    const int* edst = ei + N_EDGES;

    char* ws = (char*)d_ws;
    size_t off = 0;
    auto alloc = [&](size_t bytes) { char* p = ws + off; off = (off + bytes + 255) & ~(size_t)255; return p; };
    __bf16* Hb     = (__bf16*)alloc((size_t)N_NODES * D1 * 2);     // 51.2 MB
    __bf16* out1   = (__bf16*)alloc((size_t)N_NODES * D1 * 2);     // 51.2 MB
    __bf16* Xb     = (__bf16*)alloc((size_t)N_NODES * IN_CH * 2);  // 25.6 MB
    __bf16* Wt     = (__bf16*)alloc((size_t)D1 * IN_CH * 2);       // 0.26 MB
    float* a_src1  = (float*)alloc((size_t)N_NODES * HEADS * 4);
    float* a_dst1  = (float*)alloc((size_t)N_NODES * HEADS * 4);
    float* h2      = (float*)alloc((size_t)N_NODES * OUT_CH * 4);
    float* a_src2  = (float*)alloc((size_t)N_NODES * 4);
    float* a_dst2  = (float*)alloc((size_t)N_NODES * 4);
    int*   deg     = (int*)alloc((size_t)N_NODES * 4);
    int*   offsets = (int*)alloc((size_t)(N_NODES + 1) * 4);
    int*   cursor  = (int*)alloc((size_t)N_NODES * 4);
    int*   csr     = (int*)alloc((size_t)N_EDGES * 4);
    int*   bsum    = (int*)alloc(64 * 4);
    int*   bpre    = (int*)alloc(64 * 4);
    (void)ws_size;

    // 0. converts
    k_cvt_x<<<(N_NODES * IN_CH / 8 + 255) / 256, 256, 0, stream>>>(x, Xb);
    k_cvt_w1<<<(D1 * IN_CH + 255) / 256, 256, 0, stream>>>(W1, Wt);
    // 1. GEMM1 (MFMA) + fused att1 logits, bf16 H out
    dim3 g1((N_NODES + 127) / 128, D1 / 128);
    k_gemm1_mfma<<<g1, 256, 0, stream>>>(Xb, Wt, att_src1, att_dst1, Hb, a_src1, a_dst1);
    // 2. CSR build
    k_zero<<<(N_NODES + 255) / 256, 256, 0, stream>>>(deg);
    k_hist<<<(N_EDGES + 255) / 256, 256, 0, stream>>>(edst, deg);
    int nb = (N_NODES + 1023) / 1024;
    k_scan1<<<nb, 1024, 0, stream>>>(deg, offsets, bsum);
    k_scan2<<<1, 64, 0, stream>>>(bsum, bpre, offsets);
    k_scan3<<<(N_NODES + 255) / 256, 256, 0, stream>>>(offsets, bpre, cursor);
    k_scatter<<<(N_EDGES + 255) / 256, 256, 0, stream>>>(esrc, edst, cursor, csr);
    // 3. layer-1 aggregation (+bias+ELU), bf16 in/out
    k_agg1<<<(N_NODES * 64 + 255) / 256, 256, 0, stream>>>(Hb, a_src1, a_dst1, offsets, csr, b1, out1);
    // 4. GEMM2 + layer-2 logits
    k_gemm2<<<(N_NODES + 15) / 16, 256, 0, stream>>>(out1, W2, att_src2, att_dst2, h2, a_src2, a_dst2);
    // 5. layer-2 aggregation + bias + log_softmax
    k_agg2<<<(N_NODES * 64 + 255) / 256, 256, 0, stream>>>(h2, a_src2, a_dst2, offsets, csr, b2, out);
}

// Round 4
// 359.618 us; speedup vs baseline: 1.9705x; 1.1337x over previous
//
#include <hip/hip_runtime.h>
#include <math.h>

#define N_NODES 50000
#define N_EDGES 500000
#define IN_CH 256
#define D1 512          // HEADS*HID
#define HEADS 8
#define HID 64
#define OUT_CH 16
#define NEG_SLOPE 0.2f

typedef __bf16 bf16x8 __attribute__((ext_vector_type(8)));
typedef float f32x4 __attribute__((ext_vector_type(4)));

// ---------------- fp32 -> bf16 converts -------------------------------------
__global__ __launch_bounds__(256) void k_cvt_x(const float* __restrict__ X,
                                               __bf16* __restrict__ Xb) {
    size_t i = ((size_t)blockIdx.x * 256 + threadIdx.x) * 8;   // exact multiple
    float4 v0 = *(const float4*)&X[i];
    float4 v1 = *(const float4*)&X[i + 4];
    __bf16 o[8] = {(__bf16)v0.x, (__bf16)v0.y, (__bf16)v0.z, (__bf16)v0.w,
                   (__bf16)v1.x, (__bf16)v1.y, (__bf16)v1.z, (__bf16)v1.w};
    *(uint4*)&Xb[i] = *(uint4*)o;
}

// W1 [256,512] fp32 -> Wt [512,256] bf16 (transposed)
__global__ __launch_bounds__(256) void k_cvt_w1(const float* __restrict__ W,
                                                __bf16* __restrict__ Wt) {
    int idx = blockIdx.x * 256 + threadIdx.x;     // 0..131071
    int n = idx >> 8;
    int k = idx & 255;
    Wt[idx] = (__bf16)W[k * D1 + n];
}

// W2 [512,16] fp32 -> Wt2 [16,512] bf16 (transposed)
__global__ __launch_bounds__(256) void k_cvt_w2(const float* __restrict__ W,
                                                __bf16* __restrict__ Wt2) {
    int idx = blockIdx.x * 256 + threadIdx.x;     // 0..8191
    if (idx < D1 * OUT_CH) {
        int n = idx >> 9;
        int k = idx & 511;
        Wt2[idx] = (__bf16)W[k * OUT_CH + n];
    }
}

// ---------------- GEMM1 (MFMA) + fused att1 logits --------------------------
__global__ __launch_bounds__(256) void k_gemm1_mfma(const __bf16* __restrict__ Xb,
                                                    const __bf16* __restrict__ Wt,
                                                    const float* __restrict__ att_src,
                                                    const float* __restrict__ att_dst,
                                                    __bf16* __restrict__ Hb,
                                                    float* __restrict__ a_src1,
                                                    float* __restrict__ a_dst1) {
    __shared__ __bf16 As[128][40];
    __shared__ __bf16 Bs[128][40];
    int tid = threadIdx.x;
    int wid = tid >> 6, lane = tid & 63;
    int wr = wid >> 1, wc = wid & 1;           // 2x2 waves of 64x64
    int row0 = blockIdx.x * 128;
    int col0 = blockIdx.y * 128;
    int lq = lane >> 4;
    int lm = lane & 15;
    f32x4 acc[4][4] = {};
    for (int k0 = 0; k0 < IN_CH; k0 += 32) {
        #pragma unroll
        for (int it = 0; it < 2; ++it) {
            int idx = tid + it * 256;
            int r  = idx >> 2;
            int c8 = (idx & 3) * 8;
            int gr = row0 + r;
            uint4 va = (gr < N_NODES) ? *(const uint4*)&Xb[(size_t)gr * IN_CH + k0 + c8]
                                      : make_uint4(0u, 0u, 0u, 0u);
            *(uint4*)&As[r][c8] = va;
            uint4 vb = *(const uint4*)&Wt[(size_t)(col0 + r) * IN_CH + k0 + c8];
            *(uint4*)&Bs[r][c8] = vb;
        }
        __syncthreads();
        bf16x8 af[4], bfr[4];
        #pragma unroll
        for (int i = 0; i < 4; ++i) af[i]  = *(bf16x8*)&As[wr * 64 + i * 16 + lm][lq * 8];
        #pragma unroll
        for (int j = 0; j < 4; ++j) bfr[j] = *(bf16x8*)&Bs[wc * 64 + j * 16 + lm][lq * 8];
        #pragma unroll
        for (int i = 0; i < 4; ++i)
            #pragma unroll
            for (int j = 0; j < 4; ++j)
                acc[i][j] = __builtin_amdgcn_mfma_f32_16x16x32_bf16(af[i], bfr[j], acc[i][j], 0, 0, 0);
        __syncthreads();
    }
    int head = blockIdx.y * 2 + wc;
    float as_v[4], ad_v[4];
    #pragma unroll
    for (int j = 0; j < 4; ++j) {
        as_v[j] = att_src[head * HID + j * 16 + lm];
        ad_v[j] = att_dst[head * HID + j * 16 + lm];
    }
    #pragma unroll
    for (int i = 0; i < 4; ++i) {
        int rbase = row0 + wr * 64 + i * 16 + lq * 4;
        #pragma unroll
        for (int r = 0; r < 4; ++r) {
            int grow = rbase + r;
            float ps = 0.f, pd = 0.f;
            #pragma unroll
            for (int j = 0; j < 4; ++j) {
                float v = acc[i][j][r];
                ps += v * as_v[j];
                pd += v * ad_v[j];
                if (grow < N_NODES)
                    Hb[(size_t)grow * D1 + col0 + wc * 64 + j * 16 + lm] = (__bf16)v;
            }
            #pragma unroll
            for (int off = 1; off < 16; off <<= 1) {
                ps += __shfl_xor(ps, off);
                pd += __shfl_xor(pd, off);
            }
            if (lm == 0 && grow < N_NODES) {
                a_src1[grow * HEADS + head] = ps;
                a_dst1[grow * HEADS + head] = pd;
            }
        }
    }
}

// ---------------- CSR build ------------------------------------------------
__global__ void k_zero(int* __restrict__ deg) {
    int i = blockIdx.x * blockDim.x + threadIdx.x;
    if (i < N_NODES) deg[i] = 0;
}

__global__ void k_hist(const int* __restrict__ dst, int* __restrict__ deg) {
    int e = blockIdx.x * blockDim.x + threadIdx.x;
    if (e < N_EDGES) atomicAdd(&deg[dst[e]], 1);
}

__global__ __launch_bounds__(1024) void k_scan1(const int* __restrict__ deg,
                                                int* __restrict__ offsets,
                                                int* __restrict__ bsum) {
    __shared__ int wsum[16];
    int tid = threadIdx.x, lane = tid & 63, wid = tid >> 6;
    int i = blockIdx.x * 1024 + tid;
    int v = (i < N_NODES) ? deg[i] : 0;
    int x = v;
    #pragma unroll
    for (int off = 1; off < 64; off <<= 1) {
        int t = __shfl_up(x, off);
        if (lane >= off) x += t;
    }
    if (lane == 63) wsum[wid] = x;
    __syncthreads();
    if (wid == 0) {
        int s = (lane < 16) ? wsum[lane] : 0;
        #pragma unroll
        for (int off = 1; off < 16; off <<= 1) {
            int t = __shfl_up(s, off);
            if (lane >= off) s += t;
        }
        if (lane < 16) wsum[lane] = s;
    }
    __syncthreads();
    int wbase = wid ? wsum[wid - 1] : 0;
    if (i < N_NODES) offsets[i] = wbase + x - v;
    if (tid == 1023) bsum[blockIdx.x] = wsum[15];
}

__global__ __launch_bounds__(64) void k_scan2(const int* __restrict__ bsum,
                                              int* __restrict__ bpre,
                                              int* __restrict__ offsets) {
    int tid = threadIdx.x;
    int nb = (N_NODES + 1023) / 1024;
    int v = (tid < nb) ? bsum[tid] : 0;
    int x = v;
    #pragma unroll
    for (int off = 1; off < 64; off <<= 1) {
        int t = __shfl_up(x, off);
        if (tid >= off) x += t;
    }
    if (tid < nb) bpre[tid] = x - v;
    if (tid == 63) offsets[N_NODES] = x;
}

__global__ void k_scan3(int* __restrict__ offsets, const int* __restrict__ bpre,
                        int* __restrict__ cursor) {
    int i = blockIdx.x * blockDim.x + threadIdx.x;
    if (i < N_NODES) {
        int o = offsets[i] + bpre[i >> 10];
        offsets[i] = o;
        cursor[i] = o;
    }
}

__global__ void k_scatter(const int* __restrict__ esrc, const int* __restrict__ edst,
                          int* __restrict__ cursor, int* __restrict__ csr) {
    int e = blockIdx.x * blockDim.x + threadIdx.x;
    if (e < N_EDGES) {
        int d = edst[e];
        int pos = atomicAdd(&cursor[d], 1);
        csr[pos] = esrc[e];
    }
}

// ---------------- layer-1 aggregation: max prepass + accumulate-only --------
__global__ __launch_bounds__(256) void k_agg1(const __bf16* __restrict__ Hb,
                                              const float* __restrict__ a_src,
                                              const float* __restrict__ a_dst,
                                              const int* __restrict__ offsets,
                                              const int* __restrict__ csr,
                                              const float* __restrict__ b1,
                                              __bf16* __restrict__ OUT) {
    int wave = (blockIdx.x * blockDim.x + threadIdx.x) >> 6;
    int lane = threadIdx.x & 63;
    if (wave >= N_NODES) return;
    int d = wave;
    int head = lane >> 3;
    int sub = lane & 7;
    float ad = a_dst[d * HEADS + head];
    float es = a_src[d * HEADS + head] + ad;   // self-loop logit
    es = es > 0.f ? es : NEG_SLOPE * es;
    int beg = offsets[d], end = offsets[d + 1];
    // --- prepass: per-head max logit (8 lanes/head stride the edges) ---
    float m = es;
    for (int idx = beg + sub; idx < end; idx += 8) {
        int s = csr[idx];
        float e = a_src[s * HEADS + head] + ad;
        e = e > 0.f ? e : NEG_SLOPE * e;
        m = fmaxf(m, e);
    }
    m = fmaxf(m, __shfl_xor(m, 1));
    m = fmaxf(m, __shfl_xor(m, 2));
    m = fmaxf(m, __shfl_xor(m, 4));
    // --- main: accumulate-only (no serial chain) ---
    float wself = __expf(es - m);
    bf16x8 hs = *(const bf16x8*)&Hb[(size_t)d * D1 + lane * 8];
    float lsum = wself;
    float o[8];
    #pragma unroll
    for (int j = 0; j < 8; ++j) o[j] = wself * (float)hs[j];
    int idx = beg;
    for (; idx + 4 <= end; idx += 4) {
        int s0 = csr[idx], s1 = csr[idx + 1], s2 = csr[idx + 2], s3 = csr[idx + 3];
        float e0 = a_src[s0 * HEADS + head] + ad;
        float e1 = a_src[s1 * HEADS + head] + ad;
        float e2 = a_src[s2 * HEADS + head] + ad;
        float e3 = a_src[s3 * HEADS + head] + ad;
        e0 = e0 > 0.f ? e0 : NEG_SLOPE * e0;
        e1 = e1 > 0.f ? e1 : NEG_SLOPE * e1;
        e2 = e2 > 0.f ? e2 : NEG_SLOPE * e2;
        e3 = e3 > 0.f ? e3 : NEG_SLOPE * e3;
        bf16x8 u0 = *(const bf16x8*)&Hb[(size_t)s0 * D1 + lane * 8];
        bf16x8 u1 = *(const bf16x8*)&Hb[(size_t)s1 * D1 + lane * 8];
        bf16x8 u2 = *(const bf16x8*)&Hb[(size_t)s2 * D1 + lane * 8];
        bf16x8 u3 = *(const bf16x8*)&Hb[(size_t)s3 * D1 + lane * 8];
        float w0 = __expf(e0 - m), w1 = __expf(e1 - m);
        float w2 = __expf(e2 - m), w3 = __expf(e3 - m);
        lsum += (w0 + w1) + (w2 + w3);
        #pragma unroll
        for (int j = 0; j < 8; ++j)
            o[j] += w0 * (float)u0[j] + w1 * (float)u1[j]
                  + w2 * (float)u2[j] + w3 * (float)u3[j];
    }
    for (; idx < end; ++idx) {
        int s = csr[idx];
        float e = a_src[s * HEADS + head] + ad;
        e = e > 0.f ? e : NEG_SLOPE * e;
        float w = __expf(e - m);
        bf16x8 u = *(const bf16x8*)&Hb[(size_t)s * D1 + lane * 8];
        lsum += w;
        #pragma unroll
        for (int j = 0; j < 8; ++j) o[j] += w * (float)u[j];
    }
    float inv = 1.0f / (lsum + 1e-16f);
    __bf16 r[8];
    #pragma unroll
    for (int j = 0; j < 8; ++j) {
        float v = o[j] * inv + b1[lane * 8 + j];
        v = v > 0.f ? v : expm1f(v);     // ELU
        r[j] = (__bf16)v;
    }
    *(uint4*)&OUT[(size_t)d * D1 + lane * 8] = *(uint4*)r;
}

// ---------------- GEMM2 (MFMA, no LDS) + layer-2 logits ---------------------
// H2[N,16] = A[N,512]bf16 @ Wt2^T; Wt2 [16,512] bf16 held in registers.
__global__ __launch_bounds__(256) void k_gemm2_mfma(const __bf16* __restrict__ A,
                                                    const __bf16* __restrict__ Wt2,
                                                    const float* __restrict__ as2v,
                                                    const float* __restrict__ ad2v,
                                                    float* __restrict__ H2,
                                                    float* __restrict__ a_src2,
                                                    float* __restrict__ a_dst2) {
    int tid = threadIdx.x;
    int wid = tid >> 6, lane = tid & 63;
    int lq = lane >> 4, lm = lane & 15;
    int row0 = blockIdx.x * 64 + wid * 16;
    int arow = row0 + lm;
    const __bf16* ap = A + (size_t)(arow < N_NODES ? arow : 0) * D1;  // garbage ok, store-guarded
    f32x4 acc = {};
    #pragma unroll
    for (int k0 = 0; k0 < 16; ++k0) {
        bf16x8 af  = *(const bf16x8*)&ap[k0 * 32 + lq * 8];
        bf16x8 bfr = *(const bf16x8*)&Wt2[lm * D1 + k0 * 32 + lq * 8];
        acc = __builtin_amdgcn_mfma_f32_16x16x32_bf16(af, bfr, acc, 0, 0, 0);
    }
    float as_c = as2v[lm], ad_c = ad2v[lm];
    #pragma unroll
    for (int r = 0; r < 4; ++r) {
        int gr = row0 + lq * 4 + r;     // C/D: row=(lane>>4)*4+reg, col=lane&15
        float v = acc[r];
        if (gr < N_NODES) H2[gr * OUT_CH + lm] = v;
        float ps = v * as_c, pd = v * ad_c;
        #pragma unroll
        for (int off = 1; off < 16; off <<= 1) {
            ps += __shfl_xor(ps, off);
            pd += __shfl_xor(pd, off);
        }
        if (lm == 0 && gr < N_NODES) { a_src2[gr] = ps; a_dst2[gr] = pd; }
    }
}

// ---------------- layer-2 aggregation + bias + log_softmax ------------------
// All 64 lanes: 4 edge-groups x 16 channels; max prepass; shuffle-combine.
__global__ __launch_bounds__(256) void k_agg2(const float* __restrict__ H2,
                                              const float* __restrict__ a_src,
                                              const float* __restrict__ a_dst,
                                              const int* __restrict__ offsets,
                                              const int* __restrict__ csr,
                                              const float* __restrict__ b2,
                                              float* __restrict__ OUT) {
    int wave = (blockIdx.x * blockDim.x + threadIdx.x) >> 6;
    int lane = threadIdx.x & 63;
    if (wave >= N_NODES) return;
    int d = wave;
    int g = lane >> 4, c = lane & 15;
    float ad = a_dst[d];
    float es = a_src[d] + ad;
    es = es > 0.f ? es : NEG_SLOPE * es;
    int beg = offsets[d], end = offsets[d + 1];
    // prepass: max over all incoming logits (64-lane stride)
    float m = es;
    for (int idx = beg + lane; idx < end; idx += 64) {
        int s = csr[idx];
        float e = a_src[s] + ad;
        e = e > 0.f ? e : NEG_SLOPE * e;
        m = fmaxf(m, e);
    }
    #pragma unroll
    for (int off = 1; off < 64; off <<= 1) m = fmaxf(m, __shfl_xor(m, off));
    // main: 4 groups stride the edges
    float lsum = 0.f, o = 0.f;
    if (g == 0) {
        float w = __expf(es - m);
        lsum = w;
        o = w * H2[d * OUT_CH + c];
    }
    for (int idx = beg + g; idx < end; idx += 4) {
        int s = csr[idx];
        float e = a_src[s] + ad;
        e = e > 0.f ? e : NEG_SLOPE * e;
        float w = __expf(e - m);
        lsum += w;
        o += w * H2[s * OUT_CH + c];
    }
    o += __shfl_xor(o, 16);  o += __shfl_xor(o, 32);
    lsum += __shfl_xor(lsum, 16);  lsum += __shfl_xor(lsum, 32);
    float v = o / (lsum + 1e-16f) + b2[c];
    float mx = v;
    #pragma unroll
    for (int off = 1; off < 16; off <<= 1) mx = fmaxf(mx, __shfl_xor(mx, off));
    float se = __expf(v - mx);
    #pragma unroll
    for (int off = 1; off < 16; off <<= 1) se += __shfl_xor(se, off);
    float res = v - mx - logf(se);
    if (lane < 16) OUT[d * OUT_CH + lane] = res;
}

// ---------------- launcher --------------------------------------------------
extern "C" void kernel_launch(void* const* d_in, const int* in_sizes, int n_in,
                              void* d_out, int out_size, void* d_ws, size_t ws_size,
                              hipStream_t stream) {
    const float* x        = (const float*)d_in[0];
    const int*   ei       = (const int*)d_in[1];
    const float* W1       = (const float*)d_in[2];
    const float* att_src1 = (const float*)d_in[3];
    const float* att_dst1 = (const float*)d_in[4];
    const float* b1       = (const float*)d_in[5];
    const float* W2       = (const float*)d_in[6];
    const float* att_src2 = (const float*)d_in[7];
    const float* att_dst2 = (const float*)d_in[8];
    const float* b2       = (const float*)d_in[9];
    float* out = (float*)d_out;

    const int* esrc = ei;
    const int* edst = ei + N_EDGES;

    char* ws = (char*)d_ws;
    size_t off = 0;
    auto alloc = [&](size_t bytes) { char* p = ws + off; off = (off + bytes + 255) & ~(size_t)255; return p; };
    __bf16* Hb     = (__bf16*)alloc((size_t)N_NODES * D1 * 2);     // 51.2 MB
    __bf16* out1   = (__bf16*)alloc((size_t)N_NODES * D1 * 2);     // 51.2 MB
    __bf16* Xb     = (__bf16*)alloc((size_t)N_NODES * IN_CH * 2);  // 25.6 MB
    __bf16* Wt     = (__bf16*)alloc((size_t)D1 * IN_CH * 2);       // 0.26 MB
    __bf16* Wt2    = (__bf16*)alloc((size_t)D1 * OUT_CH * 2);      // 16 KB
    float* a_src1  = (float*)alloc((size_t)N_NODES * HEADS * 4);
    float* a_dst1  = (float*)alloc((size_t)N_NODES * HEADS * 4);
    float* h2      = (float*)alloc((size_t)N_NODES * OUT_CH * 4);
    float* a_src2  = (float*)alloc((size_t)N_NODES * 4);
    float* a_dst2  = (float*)alloc((size_t)N_NODES * 4);
    int*   deg     = (int*)alloc((size_t)N_NODES * 4);
    int*   offsets = (int*)alloc((size_t)(N_NODES + 1) * 4);
    int*   cursor  = (int*)alloc((size_t)N_NODES * 4);
    int*   csr     = (int*)alloc((size_t)N_EDGES * 4);
    int*   bsum    = (int*)alloc(64 * 4);
    int*   bpre    = (int*)alloc(64 * 4);
    (void)ws_size;

    // 0. converts
    k_cvt_x<<<(N_NODES * IN_CH / 8 + 255) / 256, 256, 0, stream>>>(x, Xb);
    k_cvt_w1<<<(D1 * IN_CH + 255) / 256, 256, 0, stream>>>(W1, Wt);
    k_cvt_w2<<<(D1 * OUT_CH + 255) / 256, 256, 0, stream>>>(W2, Wt2);
    // 1. GEMM1 (MFMA) + fused att1 logits
    dim3 g1((N_NODES + 127) / 128, D1 / 128);
    k_gemm1_mfma<<<g1, 256, 0, stream>>>(Xb, Wt, att_src1, att_dst1, Hb, a_src1, a_dst1);
    // 2. CSR build
    k_zero<<<(N_NODES + 255) / 256, 256, 0, stream>>>(deg);
    k_hist<<<(N_EDGES + 255) / 256, 256, 0, stream>>>(edst, deg);
    int nb = (N_NODES + 1023) / 1024;
    k_scan1<<<nb, 1024, 0, stream>>>(deg, offsets, bsum);
    k_scan2<<<1, 64, 0, stream>>>(bsum, bpre, offsets);
    k_scan3<<<(N_NODES + 255) / 256, 256, 0, stream>>>(offsets, bpre, cursor);
    k_scatter<<<(N_EDGES + 255) / 256, 256, 0, stream>>>(esrc, edst, cursor, csr);
    // 3. layer-1 aggregation (+bias+ELU)
    k_agg1<<<(N_NODES * 64 + 255) / 256, 256, 0, stream>>>(Hb, a_src1, a_dst1, offsets, csr, b1, out1);
    // 4. GEMM2 (MFMA) + layer-2 logits
    k_gemm2_mfma<<<(N_NODES + 63) / 64, 256, 0, stream>>>(out1, Wt2, att_src2, att_dst2, h2, a_src2, a_dst2);
    // 5. layer-2 aggregation + bias + log_softmax
    k_agg2<<<(N_NODES * 64 + 255) / 256, 256, 0, stream>>>(h2, a_src2, a_dst2, offsets, csr, b2, out);
}